// Round 1
// baseline (10046.098 us; speedup 1.0000x reference)
//
#include <hip/hip_runtime.h>

// LSTMStateEstimation: 2-layer LSTM (B=64,T=256,IN=128,H=512) + FC(512->64).
// Persistent cooperative kernel: 256 WGs x 256 thr, one WG per CU.
// WG w<128: owns layer0 hidden units [4w,4w+4); WG w>=128: layer1 units.
// Phase p (0..256): layer0 computes t=p, layer1 computes t=p-1 (pipelined),
// one custom grid barrier per phase. GEMM via mfma_f32_16x16x32_bf16:
//  A = inputs [b][k] bf16 read straight from global (16B/lane frags, coalesced)
//  B = per-WG weight tile [n=16][k] bf16 pre-converted into workspace
//  D -> LDS -> fp32 gates -> fp32 cell state in LDS -> bf16 h to global (dbuf).

#define NB    64
#define SEQL  256
#define INF   128
#define HID   512
#define OUTN  64
#define NWG   256
#define NT    256
#define KW    1024            // Wt row stride (elements)
#define BH    (NB * HID)      // elements per h buffer

typedef __attribute__((ext_vector_type(8))) short   short8;
typedef __attribute__((ext_vector_type(4))) float   floatx4;

__device__ __forceinline__ unsigned short f2bf(float f) {
  union { float f; unsigned u; } v; v.f = f;
  return (unsigned short)((v.u + 0x7FFFu + ((v.u >> 16) & 1u)) >> 16); // RNE
}
__device__ __forceinline__ float bf2f(unsigned short s) {
  union { unsigned u; float f; } v; v.u = ((unsigned)s) << 16;
  return v.f;
}
__device__ __forceinline__ float sigf(float v) { return 1.f / (1.f + __expf(-v)); }
__device__ __forceinline__ float tanh_fast(float v) {
  float cv = fminf(fmaxf(v, -15.f), 15.f);
  float e = __expf(2.f * cv);
  return (e - 1.f) / (e + 1.f);
}

// Generation-counter grid barrier (cnt at bar[0], gen at bar[16]).
// Host memsets to 0 before every launch. Device(agent)-scope acq/rel.
__device__ __forceinline__ void grid_bar(unsigned* bar, unsigned* mygen) {
  __syncthreads();
  if (threadIdx.x == 0) {
    unsigned target = *mygen + 1;
    unsigned prev = __hip_atomic_fetch_add(&bar[0], 1u, __ATOMIC_ACQ_REL,
                                           __HIP_MEMORY_SCOPE_AGENT);
    if (prev == NWG - 1) {
      __hip_atomic_store(&bar[0], 0u, __ATOMIC_RELAXED, __HIP_MEMORY_SCOPE_AGENT);
      __hip_atomic_store(&bar[16], target, __ATOMIC_RELEASE, __HIP_MEMORY_SCOPE_AGENT);
    } else {
      while (__hip_atomic_load(&bar[16], __ATOMIC_ACQUIRE,
                               __HIP_MEMORY_SCOPE_AGENT) < target)
        __builtin_amdgcn_s_sleep(2);
    }
  }
  ++*mygen;
  __syncthreads();
}

__global__ __launch_bounds__(NT, 1) void lstm_persist(
    const float* __restrict__ x,
    const float* __restrict__ Wih0, const float* __restrict__ Whh0,
    const float* __restrict__ bih0, const float* __restrict__ bhh0,
    const float* __restrict__ Wih1, const float* __restrict__ Whh1,
    const float* __restrict__ bih1, const float* __restrict__ bhh1,
    const float* __restrict__ Wfc,  const float* __restrict__ bfc,
    float* __restrict__ out,
    unsigned* __restrict__ bar,
    unsigned short* __restrict__ h0buf, unsigned short* __restrict__ h1buf,
    unsigned short* __restrict__ xT,    unsigned short* __restrict__ Wt)
{
  const int w    = blockIdx.x;
  const int tid  = threadIdx.x;
  const int lane = tid & 63;
  const int wave = tid >> 6;        // M-tile (16 batches) per wave
  const int quad = lane >> 4;
  const int mrow = lane & 15;

  __shared__ float g_lds[16][65];   // gates: [n][batch], pad breaks conflicts
  __shared__ float c_lds[4][64];    // fp32 cell state for this WG's 4 units
  __shared__ float bias_lds[16];

  const bool isL1 = (w >= 128);
  const int  wl   = isL1 ? (w - 128) : w;   // unit-block index within layer

  // ---- one-time: convert this WG's 16 weight rows to bf16 B-layout ----
  {
    const float* Wih = isL1 ? Wih1 : Wih0;
    const float* Whh = isL1 ? Whh1 : Whh0;
    const int Kin  = isL1 ? HID : INF;
    const int Ktot = Kin + HID;               // 1024 or 640
    unsigned short* wt = Wt + (size_t)w * (16 * KW);
    for (int idx = tid; idx < 16 * Ktot; idx += NT) {
      int n = idx / Ktot, k = idx - n * Ktot;
      int ui = n >> 2, G = n & 3;             // n = ui*4 + gate
      int r  = 4 * wl + ui + HID * G;         // global gate-row
      float v = (k < Kin) ? Wih[(size_t)r * Kin + k]
                          : Whh[(size_t)r * HID + (k - Kin)];
      wt[n * KW + k] = f2bf(v);
    }
    const float* bih = isL1 ? bih1 : bih0;
    const float* bhh = isL1 ? bhh1 : bhh0;
    if (tid < 16) {
      int ui = tid >> 2, G = tid & 3;
      int r  = 4 * wl + ui + HID * G;
      bias_lds[tid] = bih[r] + bhh[r];
    }
    c_lds[tid >> 6][tid & 63] = 0.f;
  }

  // ---- one-time: transpose x[:,w,:] -> xT[w][b][k] bf16 ----
  {
    unsigned short* xd = xT + (size_t)w * (NB * INF);
    for (int idx = tid; idx < NB * INF; idx += NT) {
      int b = idx >> 7, k = idx & (INF - 1);
      xd[idx] = f2bf(x[((size_t)b * SEQL + w) * INF + k]);
    }
  }

  unsigned mygen = 0;
  grid_bar(bar, &mygen);   // xT ready; h/c zeroed (host memset)

  const int arow = wave * 16 + mrow;   // batch row this lane's A-frag covers
  const int koff = quad * 8;
  const unsigned short* wtb = Wt + (size_t)w * (16 * KW) + mrow * KW + koff;

  for (int p = 0; p <= SEQL; ++p) {
    const bool active = isL1 ? (p >= 1) : (p < SEQL);
    if (active) {
      floatx4 acc0 = {0.f, 0.f, 0.f, 0.f};
      floatx4 acc1 = {0.f, 0.f, 0.f, 0.f};
      const unsigned short* h0prev = h0buf + ((p - 1) & 1) * BH;

      if (!isL1) {
        // layer0, step t=p:  K = [x_t(128) | h0_{t-1}(512)]
        const unsigned short* xa = xT + (size_t)p * (NB * INF) + arow * INF + koff;
        #pragma unroll
        for (int ks = 0; ks < 4; ++ks) {
          short8 a = *(const short8*)(xa + 32 * ks);
          short8 b = *(const short8*)(wtb + 32 * ks);
          if (ks & 1) acc1 = __builtin_amdgcn_mfma_f32_16x16x32_bf16(a, b, acc1, 0, 0, 0);
          else        acc0 = __builtin_amdgcn_mfma_f32_16x16x32_bf16(a, b, acc0, 0, 0, 0);
        }
        const unsigned short* ha = h0prev + arow * HID + koff;
        #pragma unroll
        for (int ks = 0; ks < 16; ++ks) {
          short8 a = *(const short8*)(ha + 32 * ks);
          short8 b = *(const short8*)(wtb + INF + 32 * ks);
          if (ks & 1) acc1 = __builtin_amdgcn_mfma_f32_16x16x32_bf16(a, b, acc1, 0, 0, 0);
          else        acc0 = __builtin_amdgcn_mfma_f32_16x16x32_bf16(a, b, acc0, 0, 0, 0);
        }
      } else {
        // layer1, step t=p-1:  K = [h0_t(512) | h1_{t-1}(512)]
        const unsigned short* ha = h0prev + arow * HID + koff;          // h0_t
        const unsigned short* hb = h1buf + (p & 1) * BH + arow * HID + koff; // h1_{t-1}
        #pragma unroll
        for (int ks = 0; ks < 16; ++ks) {
          short8 a = *(const short8*)(ha + 32 * ks);
          short8 b = *(const short8*)(wtb + 32 * ks);
          if (ks & 1) acc1 = __builtin_amdgcn_mfma_f32_16x16x32_bf16(a, b, acc1, 0, 0, 0);
          else        acc0 = __builtin_amdgcn_mfma_f32_16x16x32_bf16(a, b, acc0, 0, 0, 0);
        }
        #pragma unroll
        for (int ks = 0; ks < 16; ++ks) {
          short8 a = *(const short8*)(hb + 32 * ks);
          short8 b = *(const short8*)(wtb + HID + 32 * ks);
          if (ks & 1) acc1 = __builtin_amdgcn_mfma_f32_16x16x32_bf16(a, b, acc1, 0, 0, 0);
          else        acc0 = __builtin_amdgcn_mfma_f32_16x16x32_bf16(a, b, acc0, 0, 0, 0);
        }
      }

      floatx4 acc = acc0 + acc1;
      // D layout: col = lane&15 -> n, row = quad*4+reg -> batch-in-tile
      #pragma unroll
      for (int r = 0; r < 4; ++r)
        g_lds[mrow][wave * 16 + quad * 4 + r] = acc[r];
      __syncthreads();

      { // gate math + state update: tid -> (unit ui, batch b)
        const int ui = tid >> 6, b = tid & 63;
        float gi = g_lds[ui * 4 + 0][b] + bias_lds[ui * 4 + 0];
        float gf = g_lds[ui * 4 + 1][b] + bias_lds[ui * 4 + 1];
        float gg = g_lds[ui * 4 + 2][b] + bias_lds[ui * 4 + 2];
        float go = g_lds[ui * 4 + 3][b] + bias_lds[ui * 4 + 3];
        float iv = sigf(gi), fv = sigf(gf);
        float gv = tanh_fast(gg), ov = sigf(go);
        float c  = fv * c_lds[ui][b] + iv * gv;
        c_lds[ui][b] = c;
        float h  = ov * tanh_fast(c);
        unsigned short* hout = isL1 ? (h1buf + ((p - 1) & 1) * BH)
                                    : (h0buf + (p & 1) * BH);
        hout[b * HID + 4 * wl + ui] = f2bf(h);
      }
    }
    grid_bar(bar, &mygen);
  }

  // ---- FC head: out[b][o] = h1_255[b] . Wfc[o] + bfc[o] ----
  {
    const unsigned short* hl = h1buf + 1 * BH;   // (SEQL-1)&1 == 1
    const int b = w & 63, oblk = w >> 6;         // 256 WGs cover 64b x 4 o-blocks
    const int ol = tid >> 4, ksub = tid & 15;
    const float* wrow = Wfc + (size_t)(oblk * 16 + ol) * HID;
    float s = 0.f;
    #pragma unroll
    for (int j = 0; j < 32; ++j) {
      int k = ksub * 32 + j;
      s += bf2f(hl[b * HID + k]) * wrow[k];
    }
    __shared__ float red[16][17];
    red[ol][ksub] = s;
    __syncthreads();
    if (tid < 16) {
      float sum = 0.f;
      #pragma unroll
      for (int j = 0; j < 16; ++j) sum += red[tid][j];
      out[b * OUTN + oblk * 16 + tid] = sum + bfc[oblk * 16 + tid];
    }
  }
}

// Workspace layout (bytes):
//   [0,128)            barrier (cnt @ +0, gen @ +64)
//   [128, +131072)     h0 double buffer  2 x 64 x 512 bf16
//   [131200, +131072)  h1 double buffer
//   [262272, +4194304) xT : 256 x 64 x 128 bf16
//   [4456576,+8388608) Wt : 256 WGs x 16 x 1024 bf16
// total 12,845,184 B

extern "C" void kernel_launch(void* const* d_in, const int* in_sizes, int n_in,
                              void* d_out, int out_size, void* d_ws, size_t ws_size,
                              hipStream_t stream) {
  (void)in_sizes; (void)n_in; (void)out_size; (void)ws_size;

  char* ws = (char*)d_ws;
  unsigned*       bar = (unsigned*)(ws + 0);
  unsigned short* h0  = (unsigned short*)(ws + 128);
  unsigned short* h1  = (unsigned short*)(ws + 128 + 131072);
  unsigned short* xT  = (unsigned short*)(ws + 262272);
  unsigned short* Wt  = (unsigned short*)(ws + 4456576);

  // zero barrier + h buffers (ws is poisoned 0xAA before every launch)
  hipMemsetAsync(d_ws, 0, 262272, stream);

  const float* x    = (const float*)d_in[0];
  const float* Wih0 = (const float*)d_in[1];
  const float* Whh0 = (const float*)d_in[2];
  const float* bih0 = (const float*)d_in[3];
  const float* bhh0 = (const float*)d_in[4];
  const float* Wih1 = (const float*)d_in[5];
  const float* Whh1 = (const float*)d_in[6];
  const float* bih1 = (const float*)d_in[7];
  const float* bhh1 = (const float*)d_in[8];
  const float* Wfc  = (const float*)d_in[9];
  const float* bfc  = (const float*)d_in[10];
  float* out = (float*)d_out;

  void* args[] = {
    (void*)&x,
    (void*)&Wih0, (void*)&Whh0, (void*)&bih0, (void*)&bhh0,
    (void*)&Wih1, (void*)&Whh1, (void*)&bih1, (void*)&bhh1,
    (void*)&Wfc,  (void*)&bfc,
    (void*)&out,
    (void*)&bar, (void*)&h0, (void*)&h1, (void*)&xT, (void*)&Wt
  };
  hipLaunchCooperativeKernel((const void*)lstm_persist, dim3(NWG), dim3(NT),
                             args, 0, stream);
}

// Round 3
// 5823.729 us; speedup vs baseline: 1.7250x; 1.7250x over previous
//
#include <hip/hip_runtime.h>

// LSTMStateEstimation: 2-layer LSTM (B=64,T=256,IN=128,H=512) + FC(512->64).
// Persistent cooperative kernel, 256 WGs x 256 thr (r1's proven partition).
//  WG w<128: layer0 units [4w,4w+4); WG w>=128: layer1 units [4(w-128),+4).
//  Phase p: L0 computes t=p, L1 computes t=p-1 (pipelined), one distributed
//  grid barrier per phase (32 counters x 8 arrivals, relaxed polls, monotonic
//  targets, one agent acquire fence).
//  Weights: bf16 MFMA B-fragments resident in VGPRs (Bf[32] = 128 VGPRs,
//  fits under __launch_bounds__(256,2) -> no cooperative-residency risk).
//  A = h/x read straight from global as 16B lane frags (coalesced).

#define NB    64
#define SEQL  256
#define INF   128
#define HID   512
#define OUTN  64
#define NWG   256
#define NT    256
#define BH    (NB * HID)
#define NCNT  32
#define CADD  (NWG / NCNT)   // 8 arrivals per counter per barrier

typedef __attribute__((ext_vector_type(8))) short  short8;
typedef __attribute__((ext_vector_type(4))) float  floatx4;
typedef unsigned short u16;

__device__ __forceinline__ u16 f2bf(float f) {
  union { float f; unsigned u; } v; v.f = f;
  return (u16)((v.u + 0x7FFFu + ((v.u >> 16) & 1u)) >> 16);  // RNE
}
__device__ __forceinline__ float bf2f(u16 s) {
  union { unsigned u; float f; } v; v.u = ((unsigned)s) << 16;
  return v.f;
}
__device__ __forceinline__ float sigf(float v) { return 1.f / (1.f + __expf(-v)); }
__device__ __forceinline__ float tanh_fast(float v) {
  float cv = fminf(fmaxf(v, -15.f), 15.f);
  float e = __expf(2.f * cv);
  return (e - 1.f) / (e + 1.f);
}

// Distributed grid barrier: NCNT counters 128B apart, monotonic (never reset).
// Arrival: release fetch_add (one per WG, 8 WGs per counter line).
// Wait: wave 0 polls all counters with relaxed loads; waves 1-3 park in the
// HW s_barrier. One agent acquire fence before returning.
__device__ __forceinline__ void grid_bar(unsigned* cnt, int w, unsigned* gen) {
  __syncthreads();
  if (threadIdx.x == 0)
    __hip_atomic_fetch_add(&cnt[(w & (NCNT - 1)) * 32], 1u, __ATOMIC_RELEASE,
                           __HIP_MEMORY_SCOPE_AGENT);
  const unsigned target = ++(*gen) * CADD;
  if (threadIdx.x < 64) {
    const int lane = threadIdx.x & 63;
    for (;;) {
      unsigned v = target;
      if (lane < NCNT)
        v = __hip_atomic_load(&cnt[lane * 32], __ATOMIC_RELAXED,
                              __HIP_MEMORY_SCOPE_AGENT);
      if (__all(v >= target)) break;
      __builtin_amdgcn_s_sleep(1);
    }
  }
  __syncthreads();
  __builtin_amdgcn_fence(__ATOMIC_ACQUIRE, "agent");
}

// Pack this lane's MFMA B-fragments (one 16-row n-tile, KS k-steps) into
// registers. Row n=mrow -> gate-row r = 4*wl + (n>>2) + HID*(n&3);
// K-layout = [input(KIN) | h_prev(HID)].
template <int KS, int KIN>
__device__ __forceinline__ void load_B(short8 (&Bf)[32],
                                       const float* __restrict__ Wih,
                                       const float* __restrict__ Whh,
                                       int wl, int mrow, int quad) {
  const int n = mrow;
  const int r = 4 * wl + (n >> 2) + HID * (n & 3);
  const float* wr = Wih + (size_t)r * KIN;
  const float* hr = Whh + (size_t)r * HID - KIN;  // hr[k] = Whh[r][k-KIN]
#pragma unroll
  for (int ks = 0; ks < KS; ++ks) {
    short8 v;
#pragma unroll
    for (int j = 0; j < 8; ++j) {
      const int k = 32 * ks + quad * 8 + j;
      const float f = (k < KIN) ? wr[k] : hr[k];
      v[j] = (short)f2bf(f);
    }
    Bf[ks] = v;
  }
}

__global__ __launch_bounds__(NT, 2) void lstm_persist(
    const float* __restrict__ x,
    const float* __restrict__ Wih0, const float* __restrict__ Whh0,
    const float* __restrict__ bih0, const float* __restrict__ bhh0,
    const float* __restrict__ Wih1, const float* __restrict__ Whh1,
    const float* __restrict__ bih1, const float* __restrict__ bhh1,
    const float* __restrict__ Wfc,  const float* __restrict__ bfc,
    float* __restrict__ out,
    unsigned* __restrict__ cnt,
    u16* __restrict__ h0buf, u16* __restrict__ h1buf, u16* __restrict__ xT)
{
  const int w    = blockIdx.x;
  const int tid  = threadIdx.x;
  const int lane = tid & 63;
  const int wave = tid >> 6;      // 16-batch M-tile per wave
  const int quad = lane >> 4;
  const int mrow = lane & 15;

  __shared__ float g_lds[16][65];   // gates [n][batch] (+1 pad)
  __shared__ float c_lds[4][64];    // fp32 cell state, 4 units x 64 batch
  __shared__ float bias_lds[16];

  const bool isL1 = (w >= NWG / 2);
  const int  wl   = isL1 ? (w - NWG / 2) : w;

  // ---- one-time: weights -> register B-fragments, bias -> LDS ----
  short8 Bf[32];
  if (isL1) load_B<32, HID>(Bf, Wih1, Whh1, wl, mrow, quad);
  else      load_B<20, INF>(Bf, Wih0, Whh0, wl, mrow, quad);
  {
    const float* bih = isL1 ? bih1 : bih0;
    const float* bhh = isL1 ? bhh1 : bhh0;
    if (tid < 16) {
      const int r = 4 * wl + (tid >> 2) + HID * (tid & 3);
      bias_lds[tid] = bih[r] + bhh[r];
    }
    c_lds[tid >> 6][tid & 63] = 0.f;
  }

  // ---- one-time: transpose x[:,w,:] -> xT[w][b][k] bf16 ----
  {
    u16* xd = xT + (size_t)w * (NB * INF);
    for (int idx = tid; idx < NB * INF; idx += NT) {
      const int b = idx >> 7, k = idx & (INF - 1);
      xd[idx] = f2bf(x[((size_t)b * SEQL + w) * INF + k]);
    }
  }

  unsigned gen = 0;
  grid_bar(cnt, w, &gen);   // xT ready; h buffers zeroed by host memset

  const int arow = wave * 16 + mrow;   // batch row of this lane's A-frag
  const int koff = quad * 8;

  for (int p = 0; p <= SEQL; ++p) {
    const bool active = isL1 ? (p >= 1) : (p < SEQL);
    if (active) {
      floatx4 acc0 = {0.f, 0.f, 0.f, 0.f};
      floatx4 acc1 = {0.f, 0.f, 0.f, 0.f};
      const u16* h0prev = h0buf + ((p - 1) & 1) * BH;  // h0 at t=p-1

      if (!isL1) {
        // layer0, t=p:  K = [x_t(128) | h0_{t-1}(512)]
        const u16* xa = xT + (size_t)p * (NB * INF) + arow * INF + koff;
        const u16* ha = h0prev + arow * HID + koff;
#pragma unroll
        for (int ks = 0; ks < 4; ++ks) {
          short8 a = *(const short8*)(xa + 32 * ks);
          if (ks & 1) acc1 = __builtin_amdgcn_mfma_f32_16x16x32_bf16(a, Bf[ks], acc1, 0, 0, 0);
          else        acc0 = __builtin_amdgcn_mfma_f32_16x16x32_bf16(a, Bf[ks], acc0, 0, 0, 0);
        }
#pragma unroll
        for (int ks = 0; ks < 16; ++ks) {
          short8 a = *(const short8*)(ha + 32 * ks);
          if (ks & 1) acc1 = __builtin_amdgcn_mfma_f32_16x16x32_bf16(a, Bf[4 + ks], acc1, 0, 0, 0);
          else        acc0 = __builtin_amdgcn_mfma_f32_16x16x32_bf16(a, Bf[4 + ks], acc0, 0, 0, 0);
        }
      } else {
        // layer1, t=p-1:  K = [h0_t(512) | h1_{t-1}(512)]
        const u16* ha = h0prev + arow * HID + koff;                 // h0_{p-1}
        const u16* hb = h1buf + (p & 1) * BH + arow * HID + koff;   // h1_{p-2}
#pragma unroll
        for (int ks = 0; ks < 16; ++ks) {
          short8 a = *(const short8*)(ha + 32 * ks);
          if (ks & 1) acc1 = __builtin_amdgcn_mfma_f32_16x16x32_bf16(a, Bf[ks], acc1, 0, 0, 0);
          else        acc0 = __builtin_amdgcn_mfma_f32_16x16x32_bf16(a, Bf[ks], acc0, 0, 0, 0);
        }
#pragma unroll
        for (int ks = 0; ks < 16; ++ks) {
          short8 a = *(const short8*)(hb + 32 * ks);
          if (ks & 1) acc1 = __builtin_amdgcn_mfma_f32_16x16x32_bf16(a, Bf[16 + ks], acc1, 0, 0, 0);
          else        acc0 = __builtin_amdgcn_mfma_f32_16x16x32_bf16(a, Bf[16 + ks], acc0, 0, 0, 0);
        }
      }

      floatx4 acc = acc0 + acc1;
      // D layout (r1-verified): col=lane&15 -> n, row=quad*4+reg -> batch
#pragma unroll
      for (int r = 0; r < 4; ++r)
        g_lds[mrow][wave * 16 + quad * 4 + r] = acc[r];
      __syncthreads();

      { // gate math + state update: tid -> (unit ui, batch b)  [r1-proven]
        const int ui = tid >> 6, b = tid & 63;
        const float gi = g_lds[ui * 4 + 0][b] + bias_lds[ui * 4 + 0];
        const float gf = g_lds[ui * 4 + 1][b] + bias_lds[ui * 4 + 1];
        const float gg = g_lds[ui * 4 + 2][b] + bias_lds[ui * 4 + 2];
        const float go = g_lds[ui * 4 + 3][b] + bias_lds[ui * 4 + 3];
        const float c  = sigf(gf) * c_lds[ui][b] + sigf(gi) * tanh_fast(gg);
        c_lds[ui][b] = c;
        const float h = sigf(go) * tanh_fast(c);
        u16* hout = isL1 ? (h1buf + ((p - 1) & 1) * BH)
                         : (h0buf + (p & 1) * BH);
        hout[b * HID + 4 * wl + ui] = f2bf(h);
      }
    }
    grid_bar(cnt, w, &gen);
  }

  // ---- FC head: out[b][o] = h1_255[b] . Wfc[o] + bfc[o]  [r1-proven] ----
  {
    const u16* hl = h1buf + BH;            // h1 at t=255 lives in buffer 1
    const int b = w & 63, oblk = w >> 6;   // 256 WGs = 64 b x 4 o-blocks
    const int ol = tid >> 4, ksub = tid & 15;
    const float* wrow = Wfc + (size_t)(oblk * 16 + ol) * HID;
    float s = 0.f;
#pragma unroll
    for (int j = 0; j < 32; ++j) {
      const int k = ksub * 32 + j;
      s += bf2f(hl[(size_t)b * HID + k]) * wrow[k];
    }
    __shared__ float red[16][17];
    red[ol][ksub] = s;
    __syncthreads();
    if (tid < 16) {
      float sum = 0.f;
#pragma unroll
      for (int j = 0; j < 16; ++j) sum += red[tid][j];
      out[(size_t)b * OUTN + oblk * 16 + tid] = sum + bfc[oblk * 16 + tid];
    }
  }
}

// Workspace layout (bytes):
//   [0, 4096)            barrier counters (32 x 128B, monotonic)
//   [4096, +131072)      h0 double buffer  2 x 64 x 512 bf16
//   [135168, +131072)    h1 double buffer
//   [266240, +4194304)   xT : 256 x 64 x 128 bf16
// total 4,460,544 B.  Host memsets first 266,240 B to zero each launch.

extern "C" void kernel_launch(void* const* d_in, const int* in_sizes, int n_in,
                              void* d_out, int out_size, void* d_ws, size_t ws_size,
                              hipStream_t stream) {
  (void)in_sizes; (void)n_in; (void)out_size; (void)ws_size;

  char* ws = (char*)d_ws;
  unsigned* cnt = (unsigned*)(ws + 0);
  u16* h0 = (u16*)(ws + 4096);
  u16* h1 = (u16*)(ws + 135168);
  u16* xT = (u16*)(ws + 266240);

  hipMemsetAsync(d_ws, 0, 266240, stream);  // counters + h buffers

  const float* x    = (const float*)d_in[0];
  const float* Wih0 = (const float*)d_in[1];
  const float* Whh0 = (const float*)d_in[2];
  const float* bih0 = (const float*)d_in[3];
  const float* bhh0 = (const float*)d_in[4];
  const float* Wih1 = (const float*)d_in[5];
  const float* Whh1 = (const float*)d_in[6];
  const float* bih1 = (const float*)d_in[7];
  const float* bhh1 = (const float*)d_in[8];
  const float* Wfc  = (const float*)d_in[9];
  const float* bfc  = (const float*)d_in[10];
  float* out = (float*)d_out;

  void* args[] = {
    (void*)&x,
    (void*)&Wih0, (void*)&Whh0, (void*)&bih0, (void*)&bhh0,
    (void*)&Wih1, (void*)&Whh1, (void*)&bih1, (void*)&bhh1,
    (void*)&Wfc,  (void*)&bfc,
    (void*)&out,
    (void*)&cnt, (void*)&h0, (void*)&h1, (void*)&xT
  };
  hipError_t err = hipLaunchCooperativeKernel((const void*)lstm_persist,
                                              dim3(NWG), dim3(NT), args, 0, stream);
  if (err != hipSuccess) {
    // Co-residency is guaranteed structurally (256 blocks, >=1 block/CU on
    // 256 CUs), so a plain launch is safe if the cooperative path is refused.
    hipLaunchKernelGGL(lstm_persist, dim3(NWG), dim3(NT), 0, stream,
                       x, Wih0, Whh0, bih0, bhh0, Wih1, Whh1, bih1, bhh1,
                       Wfc, bfc, out, cnt, h0, h1, xT);
  }
}

// Round 4
// 2850.541 us; speedup vs baseline: 3.5243x; 2.0430x over previous
//
#include <hip/hip_runtime.h>

// LSTMStateEstimation: 2-layer LSTM (B=64,T=256,IN=128,H=512) + FC(512->64).
// Persistent cooperative kernel, 256 WGs x 256 thr.
//  WG w<128: layer0 units [4w,4w+4); WG w>=128: layer1 units [4(w-128),+4).
//  Phase p: L0 computes t=p, L1 computes t=p-1 (pipelined).
//
// r4 key change: FENCE-FREE cross-WG exchange. All shared data (h buffers,
// xT) is accessed via relaxed agent-scope atomic 8B ops (global sc0 sc1 ->
// coherent at MALL, bypassing non-coherent per-XCD L1/L2). The grid barrier
// is pure relaxed atomics: s_waitcnt(0) -> leaf fetch_add (32 lines) ->
// root fetch_add -> release-word store; everyone polls ONE release word.
// No agent release/acquire fences => no buffer_wbl2 / buffer_inv per phase
// (the r3 21.7us/phase cost).
//  Weights: bf16 MFMA B-fragments resident in VGPRs (Bf[32] = 128 VGPRs).

#define NB    64
#define SEQL  256
#define INF   128
#define HID   512
#define OUTN  64
#define NWG   256
#define NT    256
#define BH    (NB * HID)
#define NCNT  32
#define CADD  (NWG / NCNT)   // 8 arrivals per leaf counter per barrier

typedef __attribute__((ext_vector_type(8))) short  short8;
typedef __attribute__((ext_vector_type(4))) float  floatx4;
typedef unsigned short u16;
typedef unsigned long long u64;

__device__ __forceinline__ u16 f2bf(float f) {
  union { float f; unsigned u; } v; v.f = f;
  return (u16)((v.u + 0x7FFFu + ((v.u >> 16) & 1u)) >> 16);  // RNE
}
__device__ __forceinline__ float bf2f(u16 s) {
  union { unsigned u; float f; } v; v.u = ((unsigned)s) << 16;
  return v.f;
}
__device__ __forceinline__ float sigf(float v) { return 1.f / (1.f + __expf(-v)); }
__device__ __forceinline__ float tanh_fast(float v) {
  float cv = fminf(fmaxf(v, -15.f), 15.f);
  float e = __expf(2.f * cv);
  return (e - 1.f) / (e + 1.f);
}

// Coherent (MALL) 8B load/store: relaxed agent-scope atomics -> sc0 sc1,
// bypass per-XCD L1/L2. The backbone of the fence-free design.
__device__ __forceinline__ u64 ld8c(const u16* p) {
  return __hip_atomic_load((const u64*)p, __ATOMIC_RELAXED,
                           __HIP_MEMORY_SCOPE_AGENT);
}
__device__ __forceinline__ void st8c(u16* p, u64 v) {
  __hip_atomic_store((u64*)p, v, __ATOMIC_RELAXED, __HIP_MEMORY_SCOPE_AGENT);
}
// 16B A-fragment from coherent h memory (two 8B coherent loads).
__device__ __forceinline__ short8 ld_frag(const u16* p) {
  union { u64 u[2]; short8 s; } r;
  r.u[0] = ld8c(p);
  r.u[1] = ld8c(p + 4);
  return r.s;
}

// Fence-free grid barrier. Leaf counters (NCNT lines), one root line, one
// release word — all monotonic, zeroed by host before launch.
__device__ __forceinline__ void grid_bar(unsigned* leaf, unsigned* root,
                                         unsigned* rel, int w, unsigned* gen) {
  __syncthreads();
  const unsigned tgt = *gen + 1;
  if (threadIdx.x == 0) {
    __builtin_amdgcn_s_waitcnt(0);   // h stores ack'd at coherence point
    unsigned prev = __hip_atomic_fetch_add(&leaf[(w & (NCNT - 1)) * 32], 1u,
                                           __ATOMIC_RELAXED,
                                           __HIP_MEMORY_SCOPE_AGENT);
    if (prev == tgt * CADD - 1) {          // this WG completed its leaf
      unsigned rprev = __hip_atomic_fetch_add(root, 1u, __ATOMIC_RELAXED,
                                              __HIP_MEMORY_SCOPE_AGENT);
      if (rprev == tgt * NCNT - 1)         // all leaves complete
        __hip_atomic_store(rel, tgt, __ATOMIC_RELAXED,
                           __HIP_MEMORY_SCOPE_AGENT);
    }
  }
  if (threadIdx.x < 64) {   // wave 0 polls the single release word
    while (__hip_atomic_load(rel, __ATOMIC_RELAXED,
                             __HIP_MEMORY_SCOPE_AGENT) < tgt)
      __builtin_amdgcn_s_sleep(1);
  }
  ++*gen;
  __syncthreads();          // waves 1-3 park here until wave 0 sees release
}

// Pack this lane's MFMA B-fragments (one 16-row n-tile, KS k-steps) into
// registers. Row n=mrow -> gate-row r = 4*wl + (n>>2) + HID*(n&3);
// K-layout = [input(KIN) | h_prev(HID)].
template <int KS, int KIN>
__device__ __forceinline__ void load_B(short8 (&Bf)[32],
                                       const float* __restrict__ Wih,
                                       const float* __restrict__ Whh,
                                       int wl, int mrow, int quad) {
  const int n = mrow;
  const int r = 4 * wl + (n >> 2) + HID * (n & 3);
  const float* wr = Wih + (size_t)r * KIN;
  const float* hr = Whh + (size_t)r * HID - KIN;  // hr[k] = Whh[r][k-KIN]
#pragma unroll
  for (int ks = 0; ks < KS; ++ks) {
    short8 v;
#pragma unroll
    for (int j = 0; j < 8; ++j) {
      const int k = 32 * ks + quad * 8 + j;
      const float f = (k < KIN) ? wr[k] : hr[k];
      v[j] = (short)f2bf(f);
    }
    Bf[ks] = v;
  }
}

__global__ __launch_bounds__(NT, 2) void lstm_persist(
    const float* __restrict__ x,
    const float* __restrict__ Wih0, const float* __restrict__ Whh0,
    const float* __restrict__ bih0, const float* __restrict__ bhh0,
    const float* __restrict__ Wih1, const float* __restrict__ Whh1,
    const float* __restrict__ bih1, const float* __restrict__ bhh1,
    const float* __restrict__ Wfc,  const float* __restrict__ bfc,
    float* __restrict__ out,
    unsigned* __restrict__ leaf, unsigned* __restrict__ root,
    unsigned* __restrict__ rel,
    u16* __restrict__ h0buf, u16* __restrict__ h1buf, u16* __restrict__ xT)
{
  const int w    = blockIdx.x;
  const int tid  = threadIdx.x;
  const int lane = tid & 63;
  const int wave = tid >> 6;      // 16-batch M-tile per wave
  const int quad = lane >> 4;
  const int mrow = lane & 15;

  __shared__ float g_lds[16][65];   // gates [n][batch] (+1 pad)
  __shared__ float c_lds[4][64];    // fp32 cell state, 4 units x 64 batch
  __shared__ float bias_lds[16];

  const bool isL1 = (w >= NWG / 2);
  const int  wl   = isL1 ? (w - NWG / 2) : w;

  // ---- one-time: weights -> register B-fragments, bias -> LDS ----
  short8 Bf[32];
  if (isL1) load_B<32, HID>(Bf, Wih1, Whh1, wl, mrow, quad);
  else      load_B<20, INF>(Bf, Wih0, Whh0, wl, mrow, quad);
  {
    const float* bih = isL1 ? bih1 : bih0;
    const float* bhh = isL1 ? bhh1 : bhh0;
    if (tid < 16) {
      const int r = 4 * wl + (tid >> 2) + HID * (tid & 3);
      bias_lds[tid] = bih[r] + bhh[r];
    }
    c_lds[tid >> 6][tid & 63] = 0.f;
  }

  // ---- one-time: x[:,w,:] -> xT[w][b][k] bf16, written COHERENTLY so all
  // XCDs see it via cacheable reads later (write-through, no dirty L2) ----
  {
    u16* xd = xT + (size_t)w * (NB * INF);
    for (int idx = tid; idx < NB * (INF / 4); idx += NT) {
      const int b = idx >> 5, kq = idx & 31;     // 4 consecutive k per store
      const float* xs = x + ((size_t)b * SEQL + w) * INF + kq * 4;
      union { u16 h[4]; u64 u; } pk;
#pragma unroll
      for (int j = 0; j < 4; ++j) pk.h[j] = f2bf(xs[j]);
      st8c(xd + b * INF + kq * 4, pk.u);
    }
  }

  unsigned gen = 0;
  grid_bar(leaf, root, rel, w, &gen);   // xT ready; h zeroed by host memset

  const int arow = wave * 16 + mrow;   // batch row of this lane's A-frag
  const int koff = quad * 8;

  for (int p = 0; p <= SEQL; ++p) {
    const bool active = isL1 ? (p >= 1) : (p < SEQL);
    if (active) {
      floatx4 acc0 = {0.f, 0.f, 0.f, 0.f};
      floatx4 acc1 = {0.f, 0.f, 0.f, 0.f};
      const u16* h0prev = h0buf + ((p - 1) & 1) * BH;  // h0 at t=p-1

      if (!isL1) {
        // layer0, t=p:  K = [x_t(128) | h0_{t-1}(512)]
        const u16* xa = xT + (size_t)p * (NB * INF) + arow * INF + koff;
        const u16* ha = h0prev + arow * HID + koff;
#pragma unroll
        for (int ks = 0; ks < 4; ++ks) {       // x part: clean cacheable loads
          short8 a = *(const short8*)(xa + 32 * ks);
          if (ks & 1) acc1 = __builtin_amdgcn_mfma_f32_16x16x32_bf16(a, Bf[ks], acc1, 0, 0, 0);
          else        acc0 = __builtin_amdgcn_mfma_f32_16x16x32_bf16(a, Bf[ks], acc0, 0, 0, 0);
        }
#pragma unroll
        for (int ks = 0; ks < 16; ++ks) {      // h part: coherent loads
          short8 a = ld_frag(ha + 32 * ks);
          if (ks & 1) acc1 = __builtin_amdgcn_mfma_f32_16x16x32_bf16(a, Bf[4 + ks], acc1, 0, 0, 0);
          else        acc0 = __builtin_amdgcn_mfma_f32_16x16x32_bf16(a, Bf[4 + ks], acc0, 0, 0, 0);
        }
      } else {
        // layer1, t=p-1:  K = [h0_t(512) | h1_{t-1}(512)]
        const u16* ha = h0prev + arow * HID + koff;                 // h0_{p-1}
        const u16* hb = h1buf + (p & 1) * BH + arow * HID + koff;   // h1_{p-2}
#pragma unroll
        for (int ks = 0; ks < 16; ++ks) {
          short8 a = ld_frag(ha + 32 * ks);
          if (ks & 1) acc1 = __builtin_amdgcn_mfma_f32_16x16x32_bf16(a, Bf[ks], acc1, 0, 0, 0);
          else        acc0 = __builtin_amdgcn_mfma_f32_16x16x32_bf16(a, Bf[ks], acc0, 0, 0, 0);
        }
#pragma unroll
        for (int ks = 0; ks < 16; ++ks) {
          short8 a = ld_frag(hb + 32 * ks);
          if (ks & 1) acc1 = __builtin_amdgcn_mfma_f32_16x16x32_bf16(a, Bf[16 + ks], acc1, 0, 0, 0);
          else        acc0 = __builtin_amdgcn_mfma_f32_16x16x32_bf16(a, Bf[16 + ks], acc0, 0, 0, 0);
        }
      }

      floatx4 acc = acc0 + acc1;
      // D layout (verified): col=lane&15 -> n, row=quad*4+reg -> batch
#pragma unroll
      for (int r = 0; r < 4; ++r)
        g_lds[mrow][wave * 16 + quad * 4 + r] = acc[r];
      __syncthreads();

      if (tid < 64) {  // gate math: thread b computes all 4 units, 1x8B store
        const int b = tid;
        union { u16 h[4]; u64 u; } pk;
#pragma unroll
        for (int ui = 0; ui < 4; ++ui) {
          const float gi = g_lds[ui * 4 + 0][b] + bias_lds[ui * 4 + 0];
          const float gf = g_lds[ui * 4 + 1][b] + bias_lds[ui * 4 + 1];
          const float gg = g_lds[ui * 4 + 2][b] + bias_lds[ui * 4 + 2];
          const float go = g_lds[ui * 4 + 3][b] + bias_lds[ui * 4 + 3];
          const float c  = sigf(gf) * c_lds[ui][b] + sigf(gi) * tanh_fast(gg);
          c_lds[ui][b] = c;
          pk.h[ui] = f2bf(sigf(go) * tanh_fast(c));
        }
        u16* hout = (isL1 ? (h1buf + ((p - 1) & 1) * BH)
                          : (h0buf + (p & 1) * BH))
                    + (size_t)b * HID + 4 * wl;
        st8c(hout, pk.u);   // coherent 8B store (4 units)
      }
      // NOTE: no __syncthreads needed here — grid_bar starts with one.
    }
    grid_bar(leaf, root, rel, w, &gen);
  }

  // ---- FC head: out[b][o] = h1_255[b] . Wfc[o] + bfc[o] ----
  {
    const u16* hl = h1buf + BH;            // h1 at t=255 lives in buffer 1
    const int b = w & 63, oblk = w >> 6;   // 256 WGs = 64 b x 4 o-blocks
    const int ol = tid >> 4, ksub = tid & 15;
    const float* wrow = Wfc + (size_t)(oblk * 16 + ol) * HID;
    float s = 0.f;
#pragma unroll
    for (int j2 = 0; j2 < 8; ++j2) {       // 32 k per thread, coherent 8B
      union { u16 h[4]; u64 u; } pk;
      pk.u = ld8c(hl + (size_t)b * HID + ksub * 32 + j2 * 4);
#pragma unroll
      for (int q = 0; q < 4; ++q)
        s += bf2f(pk.h[q]) * wrow[ksub * 32 + j2 * 4 + q];
    }
    __shared__ float red[16][17];
    red[ol][ksub] = s;
    __syncthreads();
    if (tid < 16) {
      float sum = 0.f;
#pragma unroll
      for (int j = 0; j < 16; ++j) sum += red[tid][j];
      out[(size_t)b * OUTN + oblk * 16 + tid] = sum + bfc[oblk * 16 + tid];
    }
  }
}

// Workspace layout (bytes):
//   [0, 4096)            leaf counters (32 x 128B, monotonic)
//   [4096, 4224)         root counter
//   [4224, 4352)         release word
//   [8192, +131072)      h0 double buffer  2 x 64 x 512 bf16
//   [139264, +131072)    h1 double buffer
//   [270336, +4194304)   xT : 256 x 64 x 128 bf16
// total 4,464,640 B.  Host memsets first 270,336 B to zero each launch.

extern "C" void kernel_launch(void* const* d_in, const int* in_sizes, int n_in,
                              void* d_out, int out_size, void* d_ws, size_t ws_size,
                              hipStream_t stream) {
  (void)in_sizes; (void)n_in; (void)out_size; (void)ws_size;

  char* ws = (char*)d_ws;
  unsigned* leaf = (unsigned*)(ws + 0);
  unsigned* root = (unsigned*)(ws + 4096);
  unsigned* rel  = (unsigned*)(ws + 4224);
  u16* h0 = (u16*)(ws + 8192);
  u16* h1 = (u16*)(ws + 139264);
  u16* xT = (u16*)(ws + 270336);

  hipMemsetAsync(d_ws, 0, 270336, stream);  // counters + h buffers

  const float* x    = (const float*)d_in[0];
  const float* Wih0 = (const float*)d_in[1];
  const float* Whh0 = (const float*)d_in[2];
  const float* bih0 = (const float*)d_in[3];
  const float* bhh0 = (const float*)d_in[4];
  const float* Wih1 = (const float*)d_in[5];
  const float* Whh1 = (const float*)d_in[6];
  const float* bih1 = (const float*)d_in[7];
  const float* bhh1 = (const float*)d_in[8];
  const float* Wfc  = (const float*)d_in[9];
  const float* bfc  = (const float*)d_in[10];
  float* out = (float*)d_out;

  void* args[] = {
    (void*)&x,
    (void*)&Wih0, (void*)&Whh0, (void*)&bih0, (void*)&bhh0,
    (void*)&Wih1, (void*)&Whh1, (void*)&bih1, (void*)&bhh1,
    (void*)&Wfc,  (void*)&bfc,
    (void*)&out,
    (void*)&leaf, (void*)&root, (void*)&rel,
    (void*)&h0, (void*)&h1, (void*)&xT
  };
  hipError_t err = hipLaunchCooperativeKernel((const void*)lstm_persist,
                                              dim3(NWG), dim3(NT), args, 0, stream);
  if (err != hipSuccess) {
    // 256 blocks @ <=2 blocks/CU on 256 CUs are co-resident structurally.
    hipLaunchKernelGGL(lstm_persist, dim3(NWG), dim3(NT), 0, stream,
                       x, Wih0, Whh0, bih0, bhh0, Wih1, Whh1, bih1, bhh1,
                       Wfc, bfc, out, leaf, root, rel, h0, h1, xT);
  }
}

// Round 5
// 1958.995 us; speedup vs baseline: 5.1282x; 1.4551x over previous
//
#include <hip/hip_runtime.h>

// LSTMStateEstimation: 2-layer LSTM (B=64,T=256,IN=128,H=512) + FC(512->64).
// Persistent cooperative kernel, 256 WGs x 256 thr.
//  WG w<128: layer0 units [4w,4w+4); WG w>=128: layer1 units [4(w-128),+4).
//  Phase p: L0 computes t=p, L1 computes t=p-1 (pipelined).
//
// r5 key changes vs r4 (which was request-rate-bound: 3.15M uncoalesced 8B
// atomic MALL reads/phase ~= the measured 10.8us/phase):
//  1. A-operand h loads are now COALESCED coherent loads: inline-asm
//     global_load_dwordx4 ... sc0 sc1 (bypass L1/L2 like the atomics, but
//     wave-coalesced into 64B-line fabric requests; 16B/lane). Software-
//     pipelined in 8-frag chunks via register-tied s_waitcnt vmcnt(N) asm.
//  2. Flat barrier: relaxed fetch_add on 1-of-32 leaf lines; wave 0 scans
//     all 32 leaves with relaxed loads (no root/release hops).
// Weights stay resident in VGPR/AGPR as bf16 B-fragments; h stores remain
// relaxed 8B agent atomics (write-through to coherence point, tiny volume).

#define NB    64
#define SEQL  256
#define INF   128
#define HID   512
#define OUTN  64
#define NWG   256
#define NT    256
#define BH    (NB * HID)
#define NCNT  32
#define CADD  (NWG / NCNT)   // 8 arrivals per leaf counter per barrier

typedef __attribute__((ext_vector_type(8))) short  short8;
typedef __attribute__((ext_vector_type(4))) float  floatx4;
typedef unsigned short u16;
typedef unsigned long long u64;

// Coalesced coherent 16B load (issue only; completion via TIE8 below).
#define GLD(dst, ptr, OFF)                                                  \
  asm volatile("global_load_dwordx4 %0, %1, off offset:" OFF " sc0 sc1"     \
               : "=v"(dst) : "v"(ptr))

// Wait until <=N vmem ops outstanding, tying 8 fragment registers so no
// consumer can be scheduled before the wait. vmcnt retires in issue order,
// so interleaved compiler loads only make this conservative, never unsafe.
#define TIE8(N, x0, x1, x2, x3, x4, x5, x6, x7)                             \
  asm volatile("s_waitcnt vmcnt(" N ")"                                     \
               : "+v"(x0), "+v"(x1), "+v"(x2), "+v"(x3),                    \
                 "+v"(x4), "+v"(x5), "+v"(x6), "+v"(x7))

#define MFMA(ACC, A, B) \
  ACC = __builtin_amdgcn_mfma_f32_16x16x32_bf16((A), (B), ACC, 0, 0, 0)

__device__ __forceinline__ u16 f2bf(float f) {
  union { float f; unsigned u; } v; v.f = f;
  return (u16)((v.u + 0x7FFFu + ((v.u >> 16) & 1u)) >> 16);  // RNE
}
__device__ __forceinline__ float bf2f(u16 s) {
  union { unsigned u; float f; } v; v.u = ((unsigned)s) << 16;
  return v.f;
}
__device__ __forceinline__ float sigf(float v) { return 1.f / (1.f + __expf(-v)); }
__device__ __forceinline__ float tanh_fast(float v) {
  float cv = fminf(fmaxf(v, -15.f), 15.f);
  float e = __expf(2.f * cv);
  return (e - 1.f) / (e + 1.f);
}

// Coherent (MALL) 8B atomic load/store — used for h stores, xT init, FC head.
__device__ __forceinline__ u64 ld8c(const u16* p) {
  return __hip_atomic_load((const u64*)p, __ATOMIC_RELAXED,
                           __HIP_MEMORY_SCOPE_AGENT);
}
__device__ __forceinline__ void st8c(u16* p, u64 v) {
  __hip_atomic_store((u64*)p, v, __ATOMIC_RELAXED, __HIP_MEMORY_SCOPE_AGENT);
}

// Flat fence-free grid barrier: 32 monotonic leaf counters (128B apart).
// Arrival: s_waitcnt(0) (h stores ack'd at coherence point) + relaxed add.
// Wait: wave 0 scans all 32 leaves with relaxed loads; waves 1-3 park in
// the trailing __syncthreads. No acquire fence needed: all cross-WG data
// is read via coherence-point (sc0 sc1) accesses.
__device__ __forceinline__ void grid_bar(unsigned* leaf, int w, unsigned* gen) {
  __syncthreads();
  const unsigned tgt = ++(*gen) * CADD;
  if (threadIdx.x == 0) {
    __builtin_amdgcn_s_waitcnt(0);
    __hip_atomic_fetch_add(&leaf[(w & (NCNT - 1)) * 32], 1u, __ATOMIC_RELAXED,
                           __HIP_MEMORY_SCOPE_AGENT);
  }
  if (threadIdx.x < 64) {
    const int lane = threadIdx.x & 63;
    for (;;) {
      unsigned v = tgt;
      if (lane < NCNT)
        v = __hip_atomic_load(&leaf[lane * 32], __ATOMIC_RELAXED,
                              __HIP_MEMORY_SCOPE_AGENT);
      if (__all(v >= tgt)) break;
      __builtin_amdgcn_s_sleep(1);
    }
  }
  __syncthreads();
}

// Pack this lane's MFMA B-fragments (one 16-row n-tile, KS k-steps).
// Row n=mrow -> gate-row r = 4*wl + (n>>2) + HID*(n&3); K = [in | h_prev].
template <int KS, int KIN>
__device__ __forceinline__ void load_B(short8 (&Bf)[32],
                                       const float* __restrict__ Wih,
                                       const float* __restrict__ Whh,
                                       int wl, int mrow, int quad) {
  const int n = mrow;
  const int r = 4 * wl + (n >> 2) + HID * (n & 3);
  const float* wr = Wih + (size_t)r * KIN;
  const float* hr = Whh + (size_t)r * HID - KIN;  // hr[k] = Whh[r][k-KIN]
#pragma unroll
  for (int ks = 0; ks < KS; ++ks) {
    short8 v;
#pragma unroll
    for (int j = 0; j < 8; ++j) {
      const int k = 32 * ks + quad * 8 + j;
      const float f = (k < KIN) ? wr[k] : hr[k];
      v[j] = (short)f2bf(f);
    }
    Bf[ks] = v;
  }
}

__global__ __launch_bounds__(NT, 2) void lstm_persist(
    const float* __restrict__ x,
    const float* __restrict__ Wih0, const float* __restrict__ Whh0,
    const float* __restrict__ bih0, const float* __restrict__ bhh0,
    const float* __restrict__ Wih1, const float* __restrict__ Whh1,
    const float* __restrict__ bih1, const float* __restrict__ bhh1,
    const float* __restrict__ Wfc,  const float* __restrict__ bfc,
    float* __restrict__ out,
    unsigned* __restrict__ leaf,
    u16* __restrict__ h0buf, u16* __restrict__ h1buf, u16* __restrict__ xT)
{
  const int w    = blockIdx.x;
  const int tid  = threadIdx.x;
  const int lane = tid & 63;
  const int wave = tid >> 6;      // 16-batch M-tile per wave
  const int quad = lane >> 4;
  const int mrow = lane & 15;

  __shared__ float g_lds[16][65];   // gates [n][batch] (+1 pad)
  __shared__ float c_lds[4][64];    // fp32 cell state, 4 units x 64 batch
  __shared__ float bias_lds[16];

  const bool isL1 = (w >= NWG / 2);
  const int  wl   = isL1 ? (w - NWG / 2) : w;

  // ---- one-time: weights -> register B-fragments, bias -> LDS ----
  short8 Bf[32];
  if (isL1) load_B<32, HID>(Bf, Wih1, Whh1, wl, mrow, quad);
  else      load_B<20, INF>(Bf, Wih0, Whh0, wl, mrow, quad);
  {
    const float* bih = isL1 ? bih1 : bih0;
    const float* bhh = isL1 ? bhh1 : bhh0;
    if (tid < 16) {
      const int r = 4 * wl + (tid >> 2) + HID * (tid & 3);
      bias_lds[tid] = bih[r] + bhh[r];
    }
    c_lds[tid >> 6][tid & 63] = 0.f;
  }

  // ---- one-time: x[:,w,:] -> xT[w][b][k] bf16, written coherently ----
  {
    u16* xd = xT + (size_t)w * (NB * INF);
    for (int idx = tid; idx < NB * (INF / 4); idx += NT) {
      const int b = idx >> 5, kq = idx & 31;
      const float* xs = x + ((size_t)b * SEQL + w) * INF + kq * 4;
      union { u16 h[4]; u64 u; } pk;
#pragma unroll
      for (int j = 0; j < 4; ++j) pk.h[j] = f2bf(xs[j]);
      st8c(xd + b * INF + kq * 4, pk.u);
    }
  }

  unsigned gen = 0;
  grid_bar(leaf, w, &gen);   // xT ready; h zeroed by host memset

  const int arow = wave * 16 + mrow;   // batch row of this lane's A-frag
  const int koff = quad * 8;

  for (int p = 0; p <= SEQL; ++p) {
    const bool active = isL1 ? (p >= 1) : (p < SEQL);
    if (active) {
      floatx4 acc0 = {0.f, 0.f, 0.f, 0.f};
      floatx4 acc1 = {0.f, 0.f, 0.f, 0.f};
      const u16* h0prev = h0buf + ((p - 1) & 1) * BH;  // h0 at t=p-1

      short8 f0, f1, f2, f3, f4, f5, f6, f7, f8, f9, f10, f11, f12, f13, f14, f15;

      if (!isL1) {
        // layer0, t=p:  K = [x_t(128) | h0_{t-1}(512)]
        const u16* ha = h0prev + arow * HID + koff;
        // Issue the 16 coherent h-frag loads first (hide MALL latency).
        GLD(f0,  ha, "0");   GLD(f1,  ha, "64");  GLD(f2,  ha, "128"); GLD(f3,  ha, "192");
        GLD(f4,  ha, "256"); GLD(f5,  ha, "320"); GLD(f6,  ha, "384"); GLD(f7,  ha, "448");
        GLD(f8,  ha, "512"); GLD(f9,  ha, "576"); GLD(f10, ha, "640"); GLD(f11, ha, "704");
        GLD(f12, ha, "768"); GLD(f13, ha, "832"); GLD(f14, ha, "896"); GLD(f15, ha, "960");
        // x part: cacheable loads (xT is write-once-per-launch, read-clean).
        const u16* xa = xT + (size_t)p * (NB * INF) + arow * INF + koff;
        short8 xv0 = *(const short8*)(xa + 0);
        short8 xv1 = *(const short8*)(xa + 32);
        short8 xv2 = *(const short8*)(xa + 64);
        short8 xv3 = *(const short8*)(xa + 96);
        MFMA(acc0, xv0, Bf[0]); MFMA(acc1, xv1, Bf[1]);
        MFMA(acc0, xv2, Bf[2]); MFMA(acc1, xv3, Bf[3]);
        TIE8("8", f0, f1, f2, f3, f4, f5, f6, f7);
        MFMA(acc0, f0, Bf[4]);  MFMA(acc1, f1, Bf[5]);
        MFMA(acc0, f2, Bf[6]);  MFMA(acc1, f3, Bf[7]);
        MFMA(acc0, f4, Bf[8]);  MFMA(acc1, f5, Bf[9]);
        MFMA(acc0, f6, Bf[10]); MFMA(acc1, f7, Bf[11]);
        TIE8("0", f8, f9, f10, f11, f12, f13, f14, f15);
        MFMA(acc0, f8,  Bf[12]); MFMA(acc1, f9,  Bf[13]);
        MFMA(acc0, f10, Bf[14]); MFMA(acc1, f11, Bf[15]);
        MFMA(acc0, f12, Bf[16]); MFMA(acc1, f13, Bf[17]);
        MFMA(acc0, f14, Bf[18]); MFMA(acc1, f15, Bf[19]);
      } else {
        // layer1, t=p-1:  K = [h0_{p-1}(512) | h1_{p-2}(512)]
        const u16* ha = h0prev + arow * HID + koff;
        const u16* hb = h1buf + (p & 1) * BH + arow * HID + koff;
        short8 g0, g1, g2, g3, g4, g5, g6, g7, g8, g9, g10, g11, g12, g13, g14, g15;
        GLD(f0,  ha, "0");   GLD(f1,  ha, "64");  GLD(f2,  ha, "128"); GLD(f3,  ha, "192");
        GLD(f4,  ha, "256"); GLD(f5,  ha, "320"); GLD(f6,  ha, "384"); GLD(f7,  ha, "448");
        GLD(f8,  ha, "512"); GLD(f9,  ha, "576"); GLD(f10, ha, "640"); GLD(f11, ha, "704");
        GLD(f12, ha, "768"); GLD(f13, ha, "832"); GLD(f14, ha, "896"); GLD(f15, ha, "960");
        TIE8("8", f0, f1, f2, f3, f4, f5, f6, f7);
        MFMA(acc0, f0, Bf[0]); MFMA(acc1, f1, Bf[1]);
        MFMA(acc0, f2, Bf[2]); MFMA(acc1, f3, Bf[3]);
        MFMA(acc0, f4, Bf[4]); MFMA(acc1, f5, Bf[5]);
        MFMA(acc0, f6, Bf[6]); MFMA(acc1, f7, Bf[7]);
        GLD(g0,  hb, "0");   GLD(g1,  hb, "64");  GLD(g2,  hb, "128"); GLD(g3,  hb, "192");
        GLD(g4,  hb, "256"); GLD(g5,  hb, "320"); GLD(g6,  hb, "384"); GLD(g7,  hb, "448");
        GLD(g8,  hb, "512"); GLD(g9,  hb, "576"); GLD(g10, hb, "640"); GLD(g11, hb, "704");
        GLD(g12, hb, "768"); GLD(g13, hb, "832"); GLD(g14, hb, "896"); GLD(g15, hb, "960");
        TIE8("16", f8, f9, f10, f11, f12, f13, f14, f15);
        MFMA(acc0, f8,  Bf[8]);  MFMA(acc1, f9,  Bf[9]);
        MFMA(acc0, f10, Bf[10]); MFMA(acc1, f11, Bf[11]);
        MFMA(acc0, f12, Bf[12]); MFMA(acc1, f13, Bf[13]);
        MFMA(acc0, f14, Bf[14]); MFMA(acc1, f15, Bf[15]);
        TIE8("8", g0, g1, g2, g3, g4, g5, g6, g7);
        MFMA(acc0, g0, Bf[16]); MFMA(acc1, g1, Bf[17]);
        MFMA(acc0, g2, Bf[18]); MFMA(acc1, g3, Bf[19]);
        MFMA(acc0, g4, Bf[20]); MFMA(acc1, g5, Bf[21]);
        MFMA(acc0, g6, Bf[22]); MFMA(acc1, g7, Bf[23]);
        TIE8("0", g8, g9, g10, g11, g12, g13, g14, g15);
        MFMA(acc0, g8,  Bf[24]); MFMA(acc1, g9,  Bf[25]);
        MFMA(acc0, g10, Bf[26]); MFMA(acc1, g11, Bf[27]);
        MFMA(acc0, g12, Bf[28]); MFMA(acc1, g13, Bf[29]);
        MFMA(acc0, g14, Bf[30]); MFMA(acc1, g15, Bf[31]);
      }

      floatx4 acc = acc0 + acc1;
      // D layout (verified): col=lane&15 -> n, row=quad*4+reg -> batch
#pragma unroll
      for (int r = 0; r < 4; ++r)
        g_lds[mrow][wave * 16 + quad * 4 + r] = acc[r];
      __syncthreads();

      if (tid < 64) {  // gate math: thread b computes all 4 units, 1x8B store
        const int b = tid;
        union { u16 h[4]; u64 u; } pk;
#pragma unroll
        for (int ui = 0; ui < 4; ++ui) {
          const float gi = g_lds[ui * 4 + 0][b] + bias_lds[ui * 4 + 0];
          const float gf = g_lds[ui * 4 + 1][b] + bias_lds[ui * 4 + 1];
          const float gg = g_lds[ui * 4 + 2][b] + bias_lds[ui * 4 + 2];
          const float go = g_lds[ui * 4 + 3][b] + bias_lds[ui * 4 + 3];
          const float c  = sigf(gf) * c_lds[ui][b] + sigf(gi) * tanh_fast(gg);
          c_lds[ui][b] = c;
          pk.h[ui] = f2bf(sigf(go) * tanh_fast(c));
        }
        u16* hout = (isL1 ? (h1buf + ((p - 1) & 1) * BH)
                          : (h0buf + (p & 1) * BH))
                    + (size_t)b * HID + 4 * wl;
        st8c(hout, pk.u);   // coherent 8B store (4 units)
      }
    }
    grid_bar(leaf, w, &gen);
  }

  // ---- FC head: out[b][o] = h1_255[b] . Wfc[o] + bfc[o] ----
  {
    const u16* hl = h1buf + BH;            // h1 at t=255 lives in buffer 1
    const int b = w & 63, oblk = w >> 6;   // 256 WGs = 64 b x 4 o-blocks
    const int ol = tid >> 4, ksub = tid & 15;
    const float* wrow = Wfc + (size_t)(oblk * 16 + ol) * HID;
    float s = 0.f;
#pragma unroll
    for (int j2 = 0; j2 < 8; ++j2) {       // 32 k per thread, coherent 8B
      union { u16 h[4]; u64 u; } pk;
      pk.u = ld8c(hl + (size_t)b * HID + ksub * 32 + j2 * 4);
#pragma unroll
      for (int q = 0; q < 4; ++q)
        s += bf2f(pk.h[q]) * wrow[ksub * 32 + j2 * 4 + q];
    }
    __shared__ float red[16][17];
    red[ol][ksub] = s;
    __syncthreads();
    if (tid < 16) {
      float sum = 0.f;
#pragma unroll
      for (int j = 0; j < 16; ++j) sum += red[tid][j];
      out[(size_t)b * OUTN + oblk * 16 + tid] = sum + bfc[oblk * 16 + tid];
    }
  }
}

// Workspace layout (bytes):
//   [0, 4096)            leaf counters (32 x 128B, monotonic)
//   [8192, +131072)      h0 double buffer  2 x 64 x 512 bf16
//   [139264, +131072)    h1 double buffer
//   [270336, +4194304)   xT : 256 x 64 x 128 bf16
// total 4,464,640 B.  Host memsets first 270,336 B to zero each launch.

extern "C" void kernel_launch(void* const* d_in, const int* in_sizes, int n_in,
                              void* d_out, int out_size, void* d_ws, size_t ws_size,
                              hipStream_t stream) {
  (void)in_sizes; (void)n_in; (void)out_size; (void)ws_size;

  char* ws = (char*)d_ws;
  unsigned* leaf = (unsigned*)(ws + 0);
  u16* h0 = (u16*)(ws + 8192);
  u16* h1 = (u16*)(ws + 139264);
  u16* xT = (u16*)(ws + 270336);

  hipMemsetAsync(d_ws, 0, 270336, stream);  // counters + h buffers

  const float* x    = (const float*)d_in[0];
  const float* Wih0 = (const float*)d_in[1];
  const float* Whh0 = (const float*)d_in[2];
  const float* bih0 = (const float*)d_in[3];
  const float* bhh0 = (const float*)d_in[4];
  const float* Wih1 = (const float*)d_in[5];
  const float* Whh1 = (const float*)d_in[6];
  const float* bih1 = (const float*)d_in[7];
  const float* bhh1 = (const float*)d_in[8];
  const float* Wfc  = (const float*)d_in[9];
  const float* bfc  = (const float*)d_in[10];
  float* out = (float*)d_out;

  void* args[] = {
    (void*)&x,
    (void*)&Wih0, (void*)&Whh0, (void*)&bih0, (void*)&bhh0,
    (void*)&Wih1, (void*)&Whh1, (void*)&bih1, (void*)&bhh1,
    (void*)&Wfc,  (void*)&bfc,
    (void*)&out,
    (void*)&leaf, (void*)&h0, (void*)&h1, (void*)&xT
  };
  hipError_t err = hipLaunchCooperativeKernel((const void*)lstm_persist,
                                              dim3(NWG), dim3(NT), args, 0, stream);
  if (err != hipSuccess) {
    // 256 blocks @ <=2 blocks/CU on 256 CUs are co-resident structurally.
    hipLaunchKernelGGL(lstm_persist, dim3(NWG), dim3(NT), 0, stream,
                       x, Wih0, Whh0, bih0, bhh0, Wih1, Whh1, bih1, bhh1,
                       Wfc, bfc, out, leaf, h0, h1, xT);
  }
}

// Round 9
// 1698.683 us; speedup vs baseline: 5.9140x; 1.1532x over previous
//
#include <hip/hip_runtime.h>

// LSTMStateEstimation: 2-layer LSTM (B=64,T=256,IN=128,H=512) + FC(512->64).
//
// r9 = r6/r7/r8's BATCH-PARALLEL architecture on PROVEN primitives only.
// Post-mortem r6-r8: corruption was timing-dependent (absmax varied run to
// run) => bounded polls expiring => the hand-rolled sc0-only loads /
// scope-less atomics of the "fast path" can serve stale values on gfx950.
// r9 drops the fast/slow duality: ALL cross-WG exchange uses the r4/r5-
// validated set:
//   h loads : global_load_dwordx4 sc0 sc1 (MALL-coherent, coalesced) + TIE
//   h stores: 8B relaxed agent atomic stores
//   flags   : relaxed agent fetch_add / relaxed agent poll loads
// Architecture: 8 groups x 8 batches (group = blockIdx&7), 32 WGs/group
// (16 L0 + 16 L1), 128 gate-rows per WG, weights resident in VGPRs.
// No grid barrier in steady state: per-group per-t flags (target 16) +
// ring-of-8 h buffers. Wave 0 polls; waves 1-3 park in __syncthreads.
// Polls bounded (protocol bug -> visible wrong answer, never a dead GPU).

#define NB    64
#define SEQL  256
#define INF   128
#define HID   512
#define OUTN  64
#define NWG   256
#define NT    256
#define NCNT  32
#define CADD  (NWG / NCNT)
#define PBOUND 4096          // poll failsafe ~1ms; normal polls are ~us

typedef __attribute__((ext_vector_type(8))) short  short8;
typedef __attribute__((ext_vector_type(4))) float  floatx4;
typedef unsigned short u16;
typedef unsigned long long u64;

#define TIE8(N, x0,x1,x2,x3,x4,x5,x6,x7)                                    \
  asm volatile("s_waitcnt vmcnt(" N ")"                                     \
               : "+v"(x0), "+v"(x1), "+v"(x2), "+v"(x3),                    \
                 "+v"(x4), "+v"(x5), "+v"(x6), "+v"(x7))
#define TIE4(N, x0,x1,x2,x3)                                                \
  asm volatile("s_waitcnt vmcnt(" N ")" : "+v"(x0), "+v"(x1), "+v"(x2), "+v"(x3))

#define MFMA(ACC, A, B) \
  ACC = __builtin_amdgcn_mfma_f32_16x16x32_bf16((A), (B), ACC, 0, 0, 0)

__device__ __forceinline__ u16 f2bf(float f) {
  union { float f; unsigned u; } v; v.f = f;
  return (u16)((v.u + 0x7FFFu + ((v.u >> 16) & 1u)) >> 16);  // RNE
}
__device__ __forceinline__ float bf2f(u16 s) {
  union { unsigned u; float f; } v; v.u = ((unsigned)s) << 16;
  return v.f;
}
__device__ __forceinline__ float sigf(float v) { return 1.f / (1.f + __expf(-v)); }
__device__ __forceinline__ float tanh_fast(float v) {
  float cv = fminf(fmaxf(v, -15.f), 15.f);
  float e = __expf(2.f * cv);
  return (e - 1.f) / (e + 1.f);
}

// ---- proven exchange primitives (r4/r5-validated on MI355X) ----
// MALL-coherent coalesced 16B load; completion via TIE.
__device__ __forceinline__ short8 ldh(const u16* p) {
  short8 d;
  asm volatile("global_load_dwordx4 %0, %1, off sc0 sc1" : "=v"(d) : "v"(p));
  return d;
}
// MALL-coherent 8B store (compiler-emitted agent atomic).
__device__ __forceinline__ void st8c(u16* p, u64 v) {
  __hip_atomic_store((u64*)p, v, __ATOMIC_RELAXED, __HIP_MEMORY_SCOPE_AGENT);
}
__device__ __forceinline__ void flag_add(unsigned* p) {
  __hip_atomic_fetch_add(p, 1u, __ATOMIC_RELAXED, __HIP_MEMORY_SCOPE_AGENT);
}
// Wave 0: lane 0 polls pa, lane 1 polls pb (either may be null); waves 1-3
// park in the trailing __syncthreads. Bounded.
__device__ __forceinline__ void wait2(const unsigned* pa, const unsigned* pb) {
  if (threadIdx.x < 64) {
    const int lane = threadIdx.x;
    const unsigned* p = (lane == 0) ? pa : (lane == 1 ? pb : nullptr);
    for (int i = 0; i < PBOUND; ++i) {
      unsigned v = 16u;
      if (p) v = __hip_atomic_load(p, __ATOMIC_RELAXED,
                                   __HIP_MEMORY_SCOPE_AGENT);
      if (__all(v >= 16u)) break;
      __builtin_amdgcn_s_sleep(1);
    }
  }
  __syncthreads();
}

// One-time MALL grid barrier (r5-proven shape), bounded poll.
__device__ __forceinline__ void grid_bar_once(unsigned* leaf, int w) {
  asm volatile("s_waitcnt vmcnt(0)" ::: "memory");
  __syncthreads();
  if (threadIdx.x == 0)
    __hip_atomic_fetch_add(&leaf[(w & (NCNT - 1)) * 32], 1u, __ATOMIC_RELAXED,
                           __HIP_MEMORY_SCOPE_AGENT);
  if (threadIdx.x < 64) {
    const int lane = threadIdx.x & 63;
    for (int i = 0; i < (1 << 16); ++i) {
      unsigned v = CADD;
      if (lane < NCNT)
        v = __hip_atomic_load(&leaf[lane * 32], __ATOMIC_RELAXED,
                              __HIP_MEMORY_SCOPE_AGENT);
      if (__all(v >= CADD)) break;
      __builtin_amdgcn_s_sleep(1);
    }
  }
  __syncthreads();
}

// B-fragments: 2 n-tiles (rowid = wv*32 + t2*16 + mrow) x KS k-steps.
// rowid -> unit u = rowid>>2, gate G = rowid&3; gate-row r = G*512+32*li+u.
// K-layout = [input(KIN) | h_prev(512)].
template <int KS, int KIN>
__device__ __forceinline__ void load_B(short8 (&Bf)[2][32],
                                       const float* __restrict__ Wih,
                                       const float* __restrict__ Whh,
                                       int li, int wv, int mrow, int quad) {
#pragma unroll
  for (int t2 = 0; t2 < 2; ++t2) {
    const int rowid = wv * 32 + t2 * 16 + mrow;
    const int r = (rowid & 3) * HID + 32 * li + (rowid >> 2);
    const float* wr = Wih + (size_t)r * KIN;
    const float* hr = Whh + (size_t)r * HID - KIN;   // hr[k]=Whh[r][k-KIN]
#pragma unroll
    for (int ks = 0; ks < KS; ++ks) {
      short8 v;
#pragma unroll
      for (int j = 0; j < 8; ++j) {
        const int k = 32 * ks + quad * 8 + j;
        v[j] = (short)f2bf(k < KIN ? wr[k] : hr[k]);
      }
      Bf[t2][ks] = v;
    }
  }
}

__global__ __launch_bounds__(NT, 1) void lstm_groups(
    const float* __restrict__ x,
    const float* __restrict__ Wih0, const float* __restrict__ Whh0,
    const float* __restrict__ bih0, const float* __restrict__ bhh0,
    const float* __restrict__ Wih1, const float* __restrict__ Whh1,
    const float* __restrict__ bih1, const float* __restrict__ bhh1,
    const float* __restrict__ Wfc,  const float* __restrict__ bfc,
    float* __restrict__ out,
    unsigned* __restrict__ leaf,
    unsigned* __restrict__ flag0, unsigned* __restrict__ flag1,
    u16* __restrict__ h0r, u16* __restrict__ h1r, u16* __restrict__ xg)
{
  const int w = blockIdx.x, tid = threadIdx.x;
  const int lane = tid & 63, wv = tid >> 6;
  const int quad = lane >> 4, mrow = lane & 15;
  const int g = w & 7, m = w >> 3;          // group, member (0..31)
  const bool isL1 = (m >= 16);
  const int  li   = isL1 ? m - 16 : m;      // layer-local WG index (0..15)

  __shared__ float g_lds[128][9];
  __shared__ u64   h_lds8[8][8];
  __shared__ float bias_lds[128];
  __shared__ float red[16][17];

  // ---- xg fill: xg[g][t][b][k] bf16, 8 (g,t)-slices per WG, MALL stores ----
#pragma unroll
  for (int i = 0; i < 8; ++i) {
    const int s = w * 8 + i, gs = s >> 8, ts = s & 255;
    u16* dst = xg + (size_t)(gs * 256 + ts) * 1024;
    const int b = tid >> 5, k0 = (tid & 31) * 4;
    const float* src = x + ((size_t)(8 * gs + b) * SEQL + ts) * INF + k0;
    union { u16 h[4]; u64 u; } pk;
#pragma unroll
    for (int j = 0; j < 4; ++j) pk.h[j] = f2bf(src[j]);
    st8c(dst + b * 128 + k0, pk.u);
  }

  // ---- weights -> VGPR B-fragments; bias -> LDS ----
  short8 Bf[2][32];
  if (isL1) load_B<32, HID>(Bf, Wih1, Whh1, li, wv, mrow, quad);
  else      load_B<20, INF>(Bf, Wih0, Whh0, li, wv, mrow, quad);
  if (tid < 128) {
    const int r = (tid & 3) * HID + 32 * li + (tid >> 2);
    bias_lds[tid] = (isL1 ? bih1[r] + bhh1[r] : bih0[r] + bhh0[r]);
  }

  grid_bar_once(leaf, w);   // xg complete everywhere; rings/flags zeroed

  unsigned* flag0g = flag0 + g * 256;
  unsigned* flag1g = flag1 + g * 256;
  u16* h0g = h0r + (size_t)g * 32768;       // 8 slots x 8 b x 512 k
  u16* h1g = h1r + (size_t)g * 32768;
  const u16* xgg = xg + (size_t)g * 256 * 1024;

  float cst = 0.f;                 // fp32 cell state, thread-private
  const int ab = mrow & 7;         // batch of this lane's A row (dup 8..15)
  const int koff = quad * 8;

  for (int t = 0; t < SEQL; ++t) {
    // dependency gates (acyclic: L1[t]<-{L0[t],L1[t-1]}, L0[t]<-{L0[t-1],L1[t-8]})
    const unsigned* pa;
    const unsigned* pb;
    if (!isL1) { pa = (t >= 1) ? flag0g + (t - 1) : nullptr;   // cohort lockstep
                 pb = (t >= 8) ? flag1g + (t - 8) : nullptr; } // ring-8 WAR gate
    else       { pa = flag0g + t;                              // h0_t ready
                 pb = (t >= 1) ? flag1g + (t - 1) : nullptr; } // lockstep + WAR
    wait2(pa, pb);

    floatx4 a00 = {0,0,0,0}, a01 = {0,0,0,0}, a10 = {0,0,0,0}, a11 = {0,0,0,0};
    short8 f0,f1,f2,f3,f4,f5,f6,f7,f8,f9,f10,f11,f12,f13,f14,f15;

    if (!isL1) {
      // layer0 @ t: K = [x_t(128) | h0_{t-1}(512)]
      const u16* ha = h0g + ((t + 7) & 7) * 4096 + ab * 512 + koff;
      f0=ldh(ha+0);    f1=ldh(ha+32);   f2=ldh(ha+64);   f3=ldh(ha+96);
      f4=ldh(ha+128);  f5=ldh(ha+160);  f6=ldh(ha+192);  f7=ldh(ha+224);
      f8=ldh(ha+256);  f9=ldh(ha+288);  f10=ldh(ha+320); f11=ldh(ha+352);
      f12=ldh(ha+384); f13=ldh(ha+416); f14=ldh(ha+448); f15=ldh(ha+480);
      const u16* xa = xgg + (size_t)t * 1024 + ab * 128 + koff;
      short8 x0 = *(const short8*)(xa +  0);
      short8 x1 = *(const short8*)(xa + 32);
      short8 x2 = *(const short8*)(xa + 64);
      short8 x3 = *(const short8*)(xa + 96);
      MFMA(a00,x0,Bf[0][0]);  MFMA(a10,x0,Bf[1][0]);
      MFMA(a01,x1,Bf[0][1]);  MFMA(a11,x1,Bf[1][1]);
      MFMA(a00,x2,Bf[0][2]);  MFMA(a10,x2,Bf[1][2]);
      MFMA(a01,x3,Bf[0][3]);  MFMA(a11,x3,Bf[1][3]);
      TIE8("8", f0,f1,f2,f3,f4,f5,f6,f7);
      MFMA(a00,f0,Bf[0][4]);  MFMA(a10,f0,Bf[1][4]);
      MFMA(a01,f1,Bf[0][5]);  MFMA(a11,f1,Bf[1][5]);
      MFMA(a00,f2,Bf[0][6]);  MFMA(a10,f2,Bf[1][6]);
      MFMA(a01,f3,Bf[0][7]);  MFMA(a11,f3,Bf[1][7]);
      MFMA(a00,f4,Bf[0][8]);  MFMA(a10,f4,Bf[1][8]);
      MFMA(a01,f5,Bf[0][9]);  MFMA(a11,f5,Bf[1][9]);
      MFMA(a00,f6,Bf[0][10]); MFMA(a10,f6,Bf[1][10]);
      MFMA(a01,f7,Bf[0][11]); MFMA(a11,f7,Bf[1][11]);
      TIE8("0", f8,f9,f10,f11,f12,f13,f14,f15);
      MFMA(a00,f8, Bf[0][12]); MFMA(a10,f8, Bf[1][12]);
      MFMA(a01,f9, Bf[0][13]); MFMA(a11,f9, Bf[1][13]);
      MFMA(a00,f10,Bf[0][14]); MFMA(a10,f10,Bf[1][14]);
      MFMA(a01,f11,Bf[0][15]); MFMA(a11,f11,Bf[1][15]);
      MFMA(a00,f12,Bf[0][16]); MFMA(a10,f12,Bf[1][16]);
      MFMA(a01,f13,Bf[0][17]); MFMA(a11,f13,Bf[1][17]);
      MFMA(a00,f14,Bf[0][18]); MFMA(a10,f14,Bf[1][18]);
      MFMA(a01,f15,Bf[0][19]); MFMA(a11,f15,Bf[1][19]);
    } else {
      // layer1 @ t: K = [h0_t(512) | h1_{t-1}(512)]
      const u16* ha = h0g + (t & 7) * 4096 + ab * 512 + koff;
      const u16* hb = h1g + ((t + 7) & 7) * 4096 + ab * 512 + koff;
      short8 g0,g1,g2,g3,g4,g5,g6,g7,g8,g9,g10,g11,g12,g13,g14,g15;
      f0=ldh(ha+0);    f1=ldh(ha+32);   f2=ldh(ha+64);   f3=ldh(ha+96);
      f4=ldh(ha+128);  f5=ldh(ha+160);  f6=ldh(ha+192);  f7=ldh(ha+224);
      f8=ldh(ha+256);  f9=ldh(ha+288);  f10=ldh(ha+320); f11=ldh(ha+352);
      f12=ldh(ha+384); f13=ldh(ha+416); f14=ldh(ha+448); f15=ldh(ha+480);
      TIE8("8", f0,f1,f2,f3,f4,f5,f6,f7);
      MFMA(a00,f0,Bf[0][0]);  MFMA(a10,f0,Bf[1][0]);
      MFMA(a01,f1,Bf[0][1]);  MFMA(a11,f1,Bf[1][1]);
      MFMA(a00,f2,Bf[0][2]);  MFMA(a10,f2,Bf[1][2]);
      MFMA(a01,f3,Bf[0][3]);  MFMA(a11,f3,Bf[1][3]);
      MFMA(a00,f4,Bf[0][4]);  MFMA(a10,f4,Bf[1][4]);
      MFMA(a01,f5,Bf[0][5]);  MFMA(a11,f5,Bf[1][5]);
      MFMA(a00,f6,Bf[0][6]);  MFMA(a10,f6,Bf[1][6]);
      MFMA(a01,f7,Bf[0][7]);  MFMA(a11,f7,Bf[1][7]);
      g0=ldh(hb+0);    g1=ldh(hb+32);   g2=ldh(hb+64);   g3=ldh(hb+96);
      g4=ldh(hb+128);  g5=ldh(hb+160);  g6=ldh(hb+192);  g7=ldh(hb+224);
      g8=ldh(hb+256);  g9=ldh(hb+288);  g10=ldh(hb+320); g11=ldh(hb+352);
      g12=ldh(hb+384); g13=ldh(hb+416); g14=ldh(hb+448); g15=ldh(hb+480);
      TIE8("16", f8,f9,f10,f11,f12,f13,f14,f15);
      MFMA(a00,f8, Bf[0][8]);  MFMA(a10,f8, Bf[1][8]);
      MFMA(a01,f9, Bf[0][9]);  MFMA(a11,f9, Bf[1][9]);
      MFMA(a00,f10,Bf[0][10]); MFMA(a10,f10,Bf[1][10]);
      MFMA(a01,f11,Bf[0][11]); MFMA(a11,f11,Bf[1][11]);
      MFMA(a00,f12,Bf[0][12]); MFMA(a10,f12,Bf[1][12]);
      MFMA(a01,f13,Bf[0][13]); MFMA(a11,f13,Bf[1][13]);
      MFMA(a00,f14,Bf[0][14]); MFMA(a10,f14,Bf[1][14]);
      MFMA(a01,f15,Bf[0][15]); MFMA(a11,f15,Bf[1][15]);
      TIE8("8", g0,g1,g2,g3,g4,g5,g6,g7);
      MFMA(a00,g0,Bf[0][16]); MFMA(a10,g0,Bf[1][16]);
      MFMA(a01,g1,Bf[0][17]); MFMA(a11,g1,Bf[1][17]);
      MFMA(a00,g2,Bf[0][18]); MFMA(a10,g2,Bf[1][18]);
      MFMA(a01,g3,Bf[0][19]); MFMA(a11,g3,Bf[1][19]);
      MFMA(a00,g4,Bf[0][20]); MFMA(a10,g4,Bf[1][20]);
      MFMA(a01,g5,Bf[0][21]); MFMA(a11,g5,Bf[1][21]);
      MFMA(a00,g6,Bf[0][22]); MFMA(a10,g6,Bf[1][22]);
      MFMA(a01,g7,Bf[0][23]); MFMA(a11,g7,Bf[1][23]);
      TIE8("0", g8,g9,g10,g11,g12,g13,g14,g15);
      MFMA(a00,g8, Bf[0][24]); MFMA(a10,g8, Bf[1][24]);
      MFMA(a01,g9, Bf[0][25]); MFMA(a11,g9, Bf[1][25]);
      MFMA(a00,g10,Bf[0][26]); MFMA(a10,g10,Bf[1][26]);
      MFMA(a01,g11,Bf[0][27]); MFMA(a11,g11,Bf[1][27]);
      MFMA(a00,g12,Bf[0][28]); MFMA(a10,g12,Bf[1][28]);
      MFMA(a01,g13,Bf[0][29]); MFMA(a11,g13,Bf[1][29]);
      MFMA(a00,g14,Bf[0][30]); MFMA(a10,g14,Bf[1][30]);
      MFMA(a01,g15,Bf[0][31]); MFMA(a11,g15,Bf[1][31]);
    }

    const floatx4 accA = a00 + a01, accB = a10 + a11;
    // D layout: col(lane&15)->rowid-in-tile, row(quad*4+reg)->batch (0-7 real)
    if (quad < 2) {
#pragma unroll
      for (int r = 0; r < 4; ++r) {
        g_lds[wv * 32 + mrow][quad * 4 + r]      = accA[r];
        g_lds[wv * 32 + 16 + mrow][quad * 4 + r] = accB[r];
      }
    }
    __syncthreads();

    {  // gate math: thread -> (batch b, unit u); c stays in a register
      const int u = tid & 31, b = tid >> 5;
      const float gi = g_lds[u * 4 + 0][b] + bias_lds[u * 4 + 0];
      const float gf = g_lds[u * 4 + 1][b] + bias_lds[u * 4 + 1];
      const float gg = g_lds[u * 4 + 2][b] + bias_lds[u * 4 + 2];
      const float go = g_lds[u * 4 + 3][b] + bias_lds[u * 4 + 3];
      const float c = sigf(gf) * cst + sigf(gi) * tanh_fast(gg);
      cst = c;
      ((u16*)&h_lds8[b][0])[u] = f2bf(sigf(go) * tanh_fast(c));
    }
    __syncthreads();

    if (tid < 64) {   // 8B MALL-coherent stores: 4 units each
      const int b = tid >> 3, u8 = tid & 7;
      const u64 v = h_lds8[b][u8];
      u16* dst = (isL1 ? h1g : h0g) + (t & 7) * 4096 + b * 512 + li * 32 + u8 * 4;
      st8c(dst, v);
    }
    asm volatile("s_waitcnt vmcnt(0)" ::: "memory");   // h in MALL before flag
    if (tid == 0) flag_add((isL1 ? flag1g : flag0g) + t);
  }

  // ---- FC head: out[b][o] = h1_255[b] . Wfc[o] + bfc[o] ----
  wait2(flag1g + 255, nullptr);
  {
    const int bloc = m >> 2, oq = m & 3;    // 32 members = 8 b x 4 o-blocks
    const int ol = tid >> 4, ksub = tid & 15;
    const u16* hp = h1g + 7 * 4096 + bloc * 512 + ksub * 32;
    short8 v0 = ldh(hp),      v1 = ldh(hp + 8);
    short8 v2 = ldh(hp + 16), v3 = ldh(hp + 24);
    TIE4("0", v0, v1, v2, v3);
    const float* wr = Wfc + (size_t)(oq * 16 + ol) * HID + ksub * 32;
    float s = 0.f;
#pragma unroll
    for (int j = 0; j < 8; ++j) {
      s += bf2f((u16)v0[j]) * wr[j];
      s += bf2f((u16)v1[j]) * wr[8 + j];
      s += bf2f((u16)v2[j]) * wr[16 + j];
      s += bf2f((u16)v3[j]) * wr[24 + j];
    }
    red[ol][ksub] = s;
    __syncthreads();
    if (tid < 16) {
      float sum = 0.f;
#pragma unroll
      for (int j = 0; j < 16; ++j) sum += red[tid][j];
      out[(size_t)(8 * g + bloc) * OUTN + oq * 16 + tid] = sum + bfc[oq * 16 + tid];
    }
  }
}

// Workspace layout (bytes):
//   [256, 4352)          one-time barrier leaves (32 x 128B)
//   [8192, 16384)        flag0[8][256] u32
//   [16384, 24576)       flag1[8][256] u32
//   [32768, 557056)      h0 rings: 8 groups x 8 slots x 8 b x 512 k bf16
//   [557056, 1081344)    h1 rings
//   [1081344, 5275648)   xg: 8 groups x 256 t x 8 b x 128 k bf16
// memset [0, 1081344) each launch (flags/rings; slot 7 = h[-1] = 0).

extern "C" void kernel_launch(void* const* d_in, const int* in_sizes, int n_in,
                              void* d_out, int out_size, void* d_ws, size_t ws_size,
                              hipStream_t stream) {
  (void)in_sizes; (void)n_in; (void)out_size; (void)ws_size;

  char* ws = (char*)d_ws;
  unsigned* leaf  = (unsigned*)(ws + 256);
  unsigned* flag0 = (unsigned*)(ws + 8192);
  unsigned* flag1 = (unsigned*)(ws + 16384);
  u16* h0r = (u16*)(ws + 32768);
  u16* h1r = (u16*)(ws + 557056);
  u16* xg  = (u16*)(ws + 1081344);

  hipMemsetAsync(d_ws, 0, 1081344, stream);

  const float* x    = (const float*)d_in[0];
  const float* Wih0 = (const float*)d_in[1];
  const float* Whh0 = (const float*)d_in[2];
  const float* bih0 = (const float*)d_in[3];
  const float* bhh0 = (const float*)d_in[4];
  const float* Wih1 = (const float*)d_in[5];
  const float* Whh1 = (const float*)d_in[6];
  const float* bih1 = (const float*)d_in[7];
  const float* bhh1 = (const float*)d_in[8];
  const float* Wfc  = (const float*)d_in[9];
  const float* bfc  = (const float*)d_in[10];
  float* out = (float*)d_out;

  void* args[] = {
    (void*)&x,
    (void*)&Wih0, (void*)&Whh0, (void*)&bih0, (void*)&bhh0,
    (void*)&Wih1, (void*)&Whh1, (void*)&bih1, (void*)&bhh1,
    (void*)&Wfc,  (void*)&bfc,
    (void*)&out,
    (void*)&leaf, (void*)&flag0, (void*)&flag1,
    (void*)&h0r, (void*)&h1r, (void*)&xg
  };
  hipError_t err = hipLaunchCooperativeKernel((const void*)lstm_groups,
                                              dim3(NWG), dim3(NT), args, 0, stream);
  if (err != hipSuccess) {
    // 256 blocks @ 1 block/CU on 256 CUs are co-resident structurally.
    hipLaunchKernelGGL(lstm_groups, dim3(NWG), dim3(NT), 0, stream,
                       x, Wih0, Whh0, bih0, bhh0, Wih1, Whh1, bih1, bhh1,
                       Wfc, bfc, out, leaf, flag0, flag1, h0r, h1r, xg);
  }
}